// Round 7
// baseline (108.548 us; speedup 1.0000x reference)
//
#include <hip/hip_runtime.h>
#include <stdint.h>

// GraphCut fused contrastive loss, MI355X (gfx950) — round 7.
// loss = -mean_i( sum_{j!=i} sign_ij * exp(sim_ij - rowmax_i) ), sim = (F F^T)/0.2.
// R6 (fused ~25us): register-pipelined, no LDS/barriers -- but L1 fragment BW
// bound: 2 MB/CU of B loads (~13.6us) vs 6.8us MFMA. R7: 2 A-tiles per wave
// halves B traffic per MFMA (1 MB/CU ~ 6.8us, balanced with MFMA). Same
// double-buffered B register pipeline. VGPR ~210 + 32 AGPR < 256 -> no spill
// (R2's trap was a forced 128 cap; R4's was no bound at all -> 64).

#define M_ROWS 8192
#define K_DIM  128
#define NCHUNK 16
#define CHUNK_COLS (M_ROWS / NCHUNK)      // 512
#define NT_PER_CHUNK (CHUNK_COLS / 32)    // 16
#define INV_T_LOG2E 7.213475204444817f    // (1/0.2) * log2(e)

typedef __bf16 bf16x8 __attribute__((ext_vector_type(8)));
typedef float  f32x16 __attribute__((ext_vector_type(16)));
typedef unsigned short ushort8v __attribute__((ext_vector_type(8)));

// FB fragment layout: 16-B granule index = (ct*16 + s8*2 + l5)*32 + lm,
// holding bf16 F[ct*32 + lm][16*s8 + 8*l5 + e], e = 0..7. A wave's fragment
// load (lane = l5*32+lm) is 64 consecutive granules = 1 KB contiguous.

// ---- prep: fp32 -> bf16 (RNE) into fragment layout + per-row self-dot ----
__global__ __launch_bounds__(256) void prep_kernel(const float* __restrict__ f,
                                                   ushort8v* __restrict__ FB,
                                                   float* __restrict__ selfdot,
                                                   float* __restrict__ out) {
    const int t    = threadIdx.x;
    const int row  = blockIdx.x * 16 + (t >> 4);
    const int slot = t & 15;                      // = s8*2 + l5
    const float4 v0 = *(const float4*)(f + (size_t)row * K_DIM + slot * 8);
    const float4 v1 = *(const float4*)(f + (size_t)row * K_DIM + slot * 8 + 4);
    float x[8] = {v0.x, v0.y, v0.z, v0.w, v1.x, v1.y, v1.z, v1.w};
    ushort8v h;
    float ss = 0.f;
#pragma unroll
    for (int e = 0; e < 8; ++e) {
        uint32_t u = __builtin_bit_cast(uint32_t, x[e]);
        uint32_t r = (u + 0x7FFFu + ((u >> 16) & 1u)) >> 16;   // RNE to bf16
        h[e] = (unsigned short)r;
        float b = __builtin_bit_cast(float, r << 16);
        ss += b * b;
    }
#pragma unroll
    for (int off = 1; off < 16; off <<= 1) ss += __shfl_xor(ss, off, 64);
    if (slot == 0) selfdot[row] = ss;
    const int ct = row >> 5, lm = row & 31;
    FB[(size_t)(ct * 16 + slot) * 32 + lm] = h;
    if (blockIdx.x == 0 && t == 0) out[0] = 0.f;   // d_out is poisoned 0xAA
}

// ---- main fused kernel: 512 blocks = 32 row-groups(256 rows) x 16 chunks ----
// Block = 4 waves; wave owns 64 rows (2 A-tiles), sweeps 16 B-tiles with a
// 2-deep register pipeline. All 4 waves share the same B sequence via L1.
__global__ __launch_bounds__(256) void fused_kernel(const ushort8v* __restrict__ FB,
                                                    const int* __restrict__ labels,
                                                    const float* __restrict__ selfdot,
                                                    float* __restrict__ partials) {
    const int blk  = blockIdx.x;
    const int rg   = blk >> 4;          // row group (256 rows)
    const int ch   = blk & 15;          // col chunk (512 cols)
    const int w    = threadIdx.x >> 6;
    const int lane = threadIdx.x & 63;
    const int lm   = lane & 31;
    const int l5   = lane >> 5;
    const int row0 = rg * 256 + w * 64;
    const int ct0  = row0 >> 5;

    // resident A fragments: 2 tiles x 8 k-slices (coalesced 1-KB wave loads)
    bf16x8 af[2][8];
#pragma unroll
    for (int tt = 0; tt < 2; ++tt)
#pragma unroll
        for (int s8 = 0; s8 < 8; ++s8)
            af[tt][s8] = (const bf16x8&)FB[(size_t)((ct0 + tt) * 16 + s8 * 2 + l5) * 32 + lm];

    // online-softmax state per owned C-row (C/D layout: row = (r&3)+8*(r>>2)+4*l5)
    float m[2][16], s[2][16];
    float minm = 1e30f;
#pragma unroll
    for (int tt = 0; tt < 2; ++tt)
#pragma unroll
        for (int r = 0; r < 16; ++r) {
            m[tt][r] = selfdot[row0 + tt * 32 + (r & 3) + 8 * (r >> 2) + 4 * l5];
            s[tt][r] = 0.f;
            minm = fminf(minm, m[tt][r]);
        }

    const int ctb0 = ch * NT_PER_CHUNK;

    auto loadB = [&](int nt, bf16x8* dst) {
#pragma unroll
        for (int s8 = 0; s8 < 8; ++s8)
            dst[s8] = (const bf16x8&)FB[(size_t)((ctb0 + nt) * 16 + s8 * 2 + l5) * 32 + lm];
    };

    auto computeTile = [&](int nt, const bf16x8* bf) {
        f32x16 a0 = {}, a1 = {};
#pragma unroll
        for (int s8 = 0; s8 < 8; ++s8) {
            a0 = __builtin_amdgcn_mfma_f32_32x32x16_bf16(af[0][s8], bf[s8], a0, 0, 0, 0);
            a1 = __builtin_amdgcn_mfma_f32_32x32x16_bf16(af[1][s8], bf[s8], a1, 0, 0, 0);
        }
        float amax = a0[0];
#pragma unroll
        for (int r = 1; r < 16; ++r) amax = fmaxf(amax, a0[r]);
#pragma unroll
        for (int r = 0; r < 16; ++r) amax = fmaxf(amax, a1[r]);
        // wave-uniform skip: exp((acc-m)/T) == 0 in fp32 when acc - m < -21
        if (__any(amax > minm - 22.f)) {
            const int jcol = (ctb0 + nt) * 32 + lm;
            const int labj = labels[jcol];
#pragma unroll
            for (int tt = 0; tt < 2; ++tt)
#pragma unroll
                for (int r = 0; r < 16; ++r) {
                    const int grow = row0 + tt * 32 + (r & 3) + 8 * (r >> 2) + 4 * l5;
                    const float acc = tt ? a1[r] : a0[r];
                    float d    = acc - m[tt][r];
                    float sign = (labj == labels[grow]) ? 1.f : -1.f;
                    if (jcol == grow) sign = 0.f;              // mask diagonal
                    bool  p = d > 0.f;
                    float e = exp2f(fminf(d, -d) * INV_T_LOG2E);
                    float xx = p ? s[tt][r] : sign;
                    float yy = p ? sign : s[tt][r];
                    s[tt][r] = fmaf(xx, e, yy);                // online rescale-or-add
                    m[tt][r] = fmaxf(m[tt][r], acc);
                }
            minm = m[0][0];
#pragma unroll
            for (int tt = 0; tt < 2; ++tt)
#pragma unroll
                for (int r = 0; r < 16; ++r) minm = fminf(minm, m[tt][r]);
        }
    };

    // 2-deep register pipeline: tile nt+1's loads fly during tile nt's compute
    bf16x8 b0[8], b1[8];
    loadB(0, b0);
    for (int nt = 0; nt < NT_PER_CHUNK; nt += 2) {
        loadB(nt + 1, b1);
        computeTile(nt, b0);
        if (nt + 2 < NT_PER_CHUNK) loadB(nt + 2, b0);
        computeTile(nt + 1, b1);
    }

    // merge the 32 column-lane partials of each row (offs stay within l5 half)
#pragma unroll
    for (int off = 1; off < 32; off <<= 1) {
#pragma unroll
        for (int tt = 0; tt < 2; ++tt)
#pragma unroll
            for (int r = 0; r < 16; ++r) {
                float mo = __shfl_xor(m[tt][r], off, 64);
                float so = __shfl_xor(s[tt][r], off, 64);
                float d  = mo - m[tt][r];
                bool  p  = d > 0.f;
                float e  = exp2f(fminf(d, -d) * INV_T_LOG2E);
                s[tt][r] = p ? fmaf(s[tt][r], e, so) : fmaf(so, e, s[tt][r]);
                m[tt][r] = fmaxf(m[tt][r], mo);
            }
    }
    if (lm == 0) {
#pragma unroll
        for (int tt = 0; tt < 2; ++tt)
#pragma unroll
            for (int r = 0; r < 16; ++r) {
                const int grow = row0 + tt * 32 + (r & 3) + 8 * (r >> 2) + 4 * l5;
                float* p = partials + ((size_t)grow * NCHUNK + ch) * 2;
                p[0] = m[tt][r];
                p[1] = s[tt][r];
            }
    }
}

// ---- merge chunk-partials per row, reduce, atomic add ----
__global__ __launch_bounds__(256) void merge_kernel(const float* __restrict__ partials,
                                                    float* __restrict__ out) {
    const int g = blockIdx.x * 256 + threadIdx.x;    // row id
    float M = -1e30f, S = 0.f;
#pragma unroll
    for (int c = 0; c < NCHUNK; ++c) {
        const float* p = partials + ((size_t)g * NCHUNK + c) * 2;
        float mo = p[0], so = p[1];
        float d  = mo - M;
        bool  pr = d > 0.f;
        float e  = exp2f(fminf(d, -d) * INV_T_LOG2E);
        S = pr ? fmaf(S, e, so) : fmaf(so, e, S);
        M = fmaxf(M, mo);
    }
    float val = -S * (1.0f / 8192.0f);
#pragma unroll
    for (int off = 1; off < 64; off <<= 1) val += __shfl_xor(val, off, 64);
    __shared__ float red[4];
    if ((threadIdx.x & 63) == 0) red[threadIdx.x >> 6] = val;
    __syncthreads();
    if (threadIdx.x == 0) atomicAdd(out, red[0] + red[1] + red[2] + red[3]);
}

extern "C" void kernel_launch(void* const* d_in, const int* in_sizes, int n_in,
                              void* d_out, int out_size, void* d_ws, size_t ws_size,
                              hipStream_t stream) {
    const float* feat   = (const float*)d_in[0];
    const int*   labels = (const int*)d_in[1];
    float*       out    = (float*)d_out;
    char*        ws     = (char*)d_ws;

    ushort8v* FB       = (ushort8v*)ws;                                          // 2 MB
    float*    selfdot  = (float*)(ws + (size_t)M_ROWS * K_DIM * 2);              // 32 KB
    float*    partials = (float*)(ws + (size_t)M_ROWS * K_DIM * 2 + M_ROWS * 4); // 1 MB

    prep_kernel<<<M_ROWS / 16, 256, 0, stream>>>(feat, FB, selfdot, out);
    fused_kernel<<<(M_ROWS / 256) * NCHUNK, 256, 0, stream>>>(FB, labels, selfdot, partials);
    merge_kernel<<<M_ROWS / 256, 256, 0, stream>>>(partials, out);
}

// Round 8
// 93.923 us; speedup vs baseline: 1.1557x; 1.1557x over previous
//
#include <hip/hip_runtime.h>
#include <stdint.h>

// GraphCut fused contrastive loss, MI355X (gfx950) — round 8.
// loss = -mean_i( sum_{j!=i} sign_ij * exp(sim_ij - rowmax_i) ), sim = (F F^T)/0.2.
// History: R3 serial loads 47us (363 TF) | R5 LDS+barriers 82us | R6 register
// 2-deep pipeline ~27us (~640 TF, best) | R7 2-A-tiles 54us (regression: NOT
// bandwidth-bound; fatter compute structure hurt).
// R8 = R6 exactly, with the B pipeline deepened to 3 buffers (prefetch
// distance 2): each B-tile load gets ~2 tile-computes to land instead of 1.
// Grid caps residency at 2 blocks/CU, so VGPR up to 256 is free here.

#define M_ROWS 8192
#define K_DIM  128
#define NCHUNK 8
#define CHUNK_COLS (M_ROWS / NCHUNK)      // 1024
#define NT_PER_CHUNK (CHUNK_COLS / 32)    // 32
#define INV_T_LOG2E 7.213475204444817f    // (1/0.2) * log2(e)

typedef __bf16 bf16x8 __attribute__((ext_vector_type(8)));
typedef float  f32x16 __attribute__((ext_vector_type(16)));
typedef unsigned short ushort8v __attribute__((ext_vector_type(8)));

// FB fragment layout: 16-B granule index = (ct*16 + s8*2 + l5)*32 + lm,
// holding bf16 F[ct*32 + lm][16*s8 + 8*l5 + e], e = 0..7. A wave's fragment
// load (lane = l5*32+lm) is 64 consecutive granules = 1 KB contiguous.

// ---- prep: fp32 -> bf16 (RNE) into fragment layout + per-row self-dot ----
__global__ __launch_bounds__(256) void prep_kernel(const float* __restrict__ f,
                                                   ushort8v* __restrict__ FB,
                                                   float* __restrict__ selfdot,
                                                   float* __restrict__ out) {
    const int t    = threadIdx.x;
    const int row  = blockIdx.x * 16 + (t >> 4);
    const int slot = t & 15;                      // = s8*2 + l5
    const float4 v0 = *(const float4*)(f + (size_t)row * K_DIM + slot * 8);
    const float4 v1 = *(const float4*)(f + (size_t)row * K_DIM + slot * 8 + 4);
    float x[8] = {v0.x, v0.y, v0.z, v0.w, v1.x, v1.y, v1.z, v1.w};
    ushort8v h;
    float ss = 0.f;
#pragma unroll
    for (int e = 0; e < 8; ++e) {
        uint32_t u = __builtin_bit_cast(uint32_t, x[e]);
        uint32_t r = (u + 0x7FFFu + ((u >> 16) & 1u)) >> 16;   // RNE to bf16
        h[e] = (unsigned short)r;
        float b = __builtin_bit_cast(float, r << 16);
        ss += b * b;
    }
#pragma unroll
    for (int off = 1; off < 16; off <<= 1) ss += __shfl_xor(ss, off, 64);
    if (slot == 0) selfdot[row] = ss;
    const int ct = row >> 5, lm = row & 31;
    FB[(size_t)(ct * 16 + slot) * 32 + lm] = h;
    if (blockIdx.x == 0 && t == 0) out[0] = 0.f;   // d_out is poisoned 0xAA
}

// ---- main fused kernel: 512 blocks = 64 row-groups(128 rows) x 8 chunks ----
__global__ __launch_bounds__(256) void fused_kernel(const ushort8v* __restrict__ FB,
                                                    const int* __restrict__ labels,
                                                    const float* __restrict__ selfdot,
                                                    float* __restrict__ partials) {
    const int blk  = blockIdx.x;
    const int rg   = blk >> 3;          // row group (128 rows)
    const int ch   = blk & 7;           // col chunk (1024 cols)
    const int w    = threadIdx.x >> 6;
    const int lane = threadIdx.x & 63;
    const int lm   = lane & 31;
    const int l5   = lane >> 5;
    const int row0 = rg * 128 + w * 32;
    const int ct0  = row0 >> 5;

    // resident A fragments (coalesced 1-KB wave loads)
    bf16x8 af[8];
#pragma unroll
    for (int s8 = 0; s8 < 8; ++s8)
        af[s8] = (const bf16x8&)FB[(size_t)(ct0 * 16 + s8 * 2 + l5) * 32 + lm];

    // online-softmax state per owned C-row (C/D layout: row = (r&3)+8*(r>>2)+4*l5)
    float m[16], s[16];
    float minm = 1e30f;
#pragma unroll
    for (int r = 0; r < 16; ++r) {
        m[r] = selfdot[row0 + (r & 3) + 8 * (r >> 2) + 4 * l5];  // diag dot ~ row max
        s[r] = 0.f;
        minm = fminf(minm, m[r]);
    }

    const int ctb0 = ch * NT_PER_CHUNK;

    auto loadB = [&](int nt, bf16x8* dst) {
#pragma unroll
        for (int s8 = 0; s8 < 8; ++s8)
            dst[s8] = (const bf16x8&)FB[(size_t)((ctb0 + nt) * 16 + s8 * 2 + l5) * 32 + lm];
    };

    auto computeTile = [&](int nt, const bf16x8* bf) {
        f32x16 acc = {};
#pragma unroll
        for (int s8 = 0; s8 < 8; ++s8)
            acc = __builtin_amdgcn_mfma_f32_32x32x16_bf16(af[s8], bf[s8], acc, 0, 0, 0);
        float amax = acc[0];
#pragma unroll
        for (int r = 1; r < 16; ++r) amax = fmaxf(amax, acc[r]);
        // wave-uniform skip: exp((acc-m)/T) == 0 in fp32 when acc - m < -21
        if (__any(amax > minm - 22.f)) {
            const int jcol = (ctb0 + nt) * 32 + lm;
            const int labj = labels[jcol];
#pragma unroll
            for (int r = 0; r < 16; ++r) {
                const int grow = row0 + (r & 3) + 8 * (r >> 2) + 4 * l5;
                float d    = acc[r] - m[r];
                float sign = (labj == labels[grow]) ? 1.f : -1.f;
                if (jcol == grow) sign = 0.f;              // mask diagonal
                bool  p = d > 0.f;
                float e = exp2f(fminf(d, -d) * INV_T_LOG2E);
                float xx = p ? s[r] : sign;
                float yy = p ? sign : s[r];
                s[r] = fmaf(xx, e, yy);                    // online rescale-or-add
                m[r] = fmaxf(m[r], acc[r]);
            }
            minm = m[0];
#pragma unroll
            for (int r = 1; r < 16; ++r) minm = fminf(minm, m[r]);
        }
    };

    // 3-deep register pipeline: tile nt's loads issue 2 tile-computes before
    // use, so ~600+ cy of latency is covered (R6's 2-deep gave only ~1 tile).
    bf16x8 B[3][8];
    loadB(0, B[0]);
    loadB(1, B[1]);
#pragma unroll
    for (int nt = 0; nt < NT_PER_CHUNK; ++nt) {
        if (nt + 2 < NT_PER_CHUNK) loadB(nt + 2, B[(nt + 2) % 3]);
        computeTile(nt, B[nt % 3]);
    }

    // merge the 32 column-lane partials of each row (offs stay within l5 half)
#pragma unroll
    for (int off = 1; off < 32; off <<= 1) {
#pragma unroll
        for (int r = 0; r < 16; ++r) {
            float mo = __shfl_xor(m[r], off, 64);
            float so = __shfl_xor(s[r], off, 64);
            float d  = mo - m[r];
            bool  p  = d > 0.f;
            float e  = exp2f(fminf(d, -d) * INV_T_LOG2E);
            s[r] = p ? fmaf(s[r], e, so) : fmaf(so, e, s[r]);
            m[r] = fmaxf(m[r], mo);
        }
    }
    if (lm == 0) {
#pragma unroll
        for (int r = 0; r < 16; ++r) {
            const int grow = row0 + (r & 3) + 8 * (r >> 2) + 4 * l5;
            float* p = partials + ((size_t)grow * NCHUNK + ch) * 2;
            p[0] = m[r];
            p[1] = s[r];
        }
    }
}

// ---- merge chunk-partials per row, reduce, atomic add ----
__global__ __launch_bounds__(256) void merge_kernel(const float* __restrict__ partials,
                                                    float* __restrict__ out) {
    const int g = blockIdx.x * 256 + threadIdx.x;    // row id
    float M = -1e30f, S = 0.f;
#pragma unroll
    for (int c = 0; c < NCHUNK; ++c) {
        const float* p = partials + ((size_t)g * NCHUNK + c) * 2;
        float mo = p[0], so = p[1];
        float d  = mo - M;
        bool  pr = d > 0.f;
        float e  = exp2f(fminf(d, -d) * INV_T_LOG2E);
        S = pr ? fmaf(S, e, so) : fmaf(so, e, S);
        M = fmaxf(M, mo);
    }
    float val = -S * (1.0f / 8192.0f);
#pragma unroll
    for (int off = 1; off < 64; off <<= 1) val += __shfl_xor(val, off, 64);
    __shared__ float red[4];
    if ((threadIdx.x & 63) == 0) red[threadIdx.x >> 6] = val;
    __syncthreads();
    if (threadIdx.x == 0) atomicAdd(out, red[0] + red[1] + red[2] + red[3]);
}

extern "C" void kernel_launch(void* const* d_in, const int* in_sizes, int n_in,
                              void* d_out, int out_size, void* d_ws, size_t ws_size,
                              hipStream_t stream) {
    const float* feat   = (const float*)d_in[0];
    const int*   labels = (const int*)d_in[1];
    float*       out    = (float*)d_out;
    char*        ws     = (char*)d_ws;

    ushort8v* FB       = (ushort8v*)ws;                                          // 2 MB
    float*    selfdot  = (float*)(ws + (size_t)M_ROWS * K_DIM * 2);              // 32 KB
    float*    partials = (float*)(ws + (size_t)M_ROWS * K_DIM * 2 + M_ROWS * 4); // 512 KB

    prep_kernel<<<M_ROWS / 16, 256, 0, stream>>>(feat, FB, selfdot, out);
    fused_kernel<<<(M_ROWS / 128) * NCHUNK, 256, 0, stream>>>(FB, labels, selfdot, partials);
    merge_kernel<<<M_ROWS / 256, 256, 0, stream>>>(partials, out);
}

// Round 10
// 88.743 us; speedup vs baseline: 1.2232x; 1.0584x over previous
//
#include <hip/hip_runtime.h>
#include <stdint.h>

// GraphCut fused contrastive loss, MI355X (gfx950) — round 10.
// loss = -mean_i( sum_{j!=i} sign_ij * exp(sim_ij - rowmax_i) ), sim = (F F^T)/0.2.
// History: R3 serial 47us | R5 LDS+barriers 82us | R6 2-deep reg pipeline ~33us
// (best bf16) | R7 2-A-tiles 54us | R8 3-deep full-unroll 42us (I-cache bloat)
// | R9 fp8 port: compile error (cvt_f32_fp8 needs immediate byte-select).
// R10 = R9 with the dequant fully constant-indexed. fp8 halves fragment bytes
// (L2->CU BW was the binder); VGPR ~110 -> 4 waves/SIMD at 1024 blocks.

#define M_ROWS 8192
#define K_DIM  128
#define NCHUNK 16
#define CHUNK_COLS (M_ROWS / NCHUNK)      // 512
#define NT_PER_CHUNK (CHUNK_COLS / 32)    // 16
#define INV_T_LOG2E 7.213475204444817f    // (1/0.2) * log2(e)

typedef float f32x16 __attribute__((ext_vector_type(16)));
typedef long  lx2    __attribute__((ext_vector_type(2)));   // 16 B = two fp8 K-slices

// FB8 layout: 16-B granule index = ((ct*4 + sp)*2 + l5)*32 + lm holding fp8
// F[ct*32 + lm][k], k = 32*sp + 8*l5 + {0..7} (low 8 B) and +16 (high 8 B).
// A wave's fragment load (lane = l5*32+lm) is 64 consecutive granules = 1 KB.

__device__ __forceinline__ float fp8_sumsq(int w) {
    float v0 = __builtin_amdgcn_cvt_f32_fp8(w, 0);
    float v1 = __builtin_amdgcn_cvt_f32_fp8(w, 1);
    float v2 = __builtin_amdgcn_cvt_f32_fp8(w, 2);
    float v3 = __builtin_amdgcn_cvt_f32_fp8(w, 3);
    return v0 * v0 + v1 * v1 + v2 * v2 + v3 * v3;
}

// ---- prep: fp32 -> fp8 e4m3 into fragment layout + per-row self-dot ----
// Self-dot computed from the DEQUANTIZED fp8 values so the online-softmax
// init matches exactly what the MFMA computes on the diagonal.
__global__ __launch_bounds__(256) void prep_kernel(const float* __restrict__ f,
                                                   int4* __restrict__ FB8,
                                                   float* __restrict__ selfdot,
                                                   float* __restrict__ out) {
    const int t   = threadIdx.x;
    const int row = blockIdx.x * 32 + (t >> 3);
    const int sub = t & 7;            // 8 threads per row
    const int sp  = sub >> 1;         // K-slice pair 0..3
    const int l5  = sub & 1;
    const float4* fr = (const float4*)(f + (size_t)row * K_DIM);
    const float4 a0 = fr[8 * sp + 2 * l5];
    const float4 a1 = fr[8 * sp + 2 * l5 + 1];
    const float4 b0 = fr[8 * sp + 2 * l5 + 4];   // +16 elements
    const float4 b1 = fr[8 * sp + 2 * l5 + 5];
    int w0 = __builtin_amdgcn_cvt_pk_fp8_f32(a0.x, a0.y, 0, false);
    w0     = __builtin_amdgcn_cvt_pk_fp8_f32(a0.z, a0.w, w0, true);
    int w1 = __builtin_amdgcn_cvt_pk_fp8_f32(a1.x, a1.y, 0, false);
    w1     = __builtin_amdgcn_cvt_pk_fp8_f32(a1.z, a1.w, w1, true);
    int w2 = __builtin_amdgcn_cvt_pk_fp8_f32(b0.x, b0.y, 0, false);
    w2     = __builtin_amdgcn_cvt_pk_fp8_f32(b0.z, b0.w, w2, true);
    int w3 = __builtin_amdgcn_cvt_pk_fp8_f32(b1.x, b1.y, 0, false);
    w3     = __builtin_amdgcn_cvt_pk_fp8_f32(b1.z, b1.w, w3, true);
    float ss = fp8_sumsq(w0) + fp8_sumsq(w1) + fp8_sumsq(w2) + fp8_sumsq(w3);
#pragma unroll
    for (int off = 1; off < 8; off <<= 1) ss += __shfl_xor(ss, off, 64);
    if (sub == 0) selfdot[row] = ss;
    const int ct = row >> 5, lm = row & 31;
    int4 st = {w0, w1, w2, w3};
    FB8[(size_t)(((ct * 4 + sp) * 2 + l5)) * 32 + lm] = st;
    if (blockIdx.x == 0 && t == 0) out[0] = 0.f;   // d_out is poisoned 0xAA
}

// ---- main fused kernel: 1024 blocks = 64 row-groups(128 rows) x 16 chunks ----
__global__ __launch_bounds__(256) void fused_kernel(const int4* __restrict__ FB8,
                                                    const int* __restrict__ labels,
                                                    const float* __restrict__ selfdot,
                                                    float* __restrict__ partials) {
    const int blk  = blockIdx.x;
    const int rg   = blk >> 4;          // row group (128 rows)
    const int ch   = blk & 15;          // col chunk (512 cols)
    const int w    = threadIdx.x >> 6;
    const int lane = threadIdx.x & 63;
    const int lm   = lane & 31;
    const int l5   = lane >> 5;
    const int row0 = rg * 128 + w * 32;
    const int ct0  = row0 >> 5;
    const lx2* FB = (const lx2*)FB8;

    // resident A fragments: 4 slice-pairs (coalesced 1-KB wave loads)
    lx2 af[4];
#pragma unroll
    for (int sp = 0; sp < 4; ++sp)
        af[sp] = FB[(size_t)((ct0 * 4 + sp) * 2 + l5) * 32 + lm];

    // online-softmax state per owned C-row (C/D layout: row = (r&3)+8*(r>>2)+4*l5)
    float m[16], s[16];
    float minm = 1e30f;
#pragma unroll
    for (int r = 0; r < 16; ++r) {
        m[r] = selfdot[row0 + (r & 3) + 8 * (r >> 2) + 4 * l5];  // diag dot ~ row max
        s[r] = 0.f;
        minm = fminf(minm, m[r]);
    }

    const int ctb0 = ch * NT_PER_CHUNK;

    auto loadB = [&](int nt, lx2* dst) {
#pragma unroll
        for (int sp = 0; sp < 4; ++sp)
            dst[sp] = FB[(size_t)(((ctb0 + nt) * 4 + sp) * 2 + l5) * 32 + lm];
    };

    auto computeTile = [&](int nt, const lx2* bf) {
        f32x16 acc = {};
#pragma unroll
        for (int sp = 0; sp < 4; ++sp) {
            acc = __builtin_amdgcn_mfma_f32_32x32x16_fp8_fp8(af[sp].x, bf[sp].x, acc, 0, 0, 0);
            acc = __builtin_amdgcn_mfma_f32_32x32x16_fp8_fp8(af[sp].y, bf[sp].y, acc, 0, 0, 0);
        }
        float amax = acc[0];
#pragma unroll
        for (int r = 1; r < 16; ++r) amax = fmaxf(amax, acc[r]);
        // wave-uniform skip: exp((acc-m)/T) == 0 in fp32 when acc - m < -21
        if (__any(amax > minm - 22.f)) {
            const int jcol = (ctb0 + nt) * 32 + lm;
            const int labj = labels[jcol];
#pragma unroll
            for (int r = 0; r < 16; ++r) {
                const int grow = row0 + (r & 3) + 8 * (r >> 2) + 4 * l5;
                float d    = acc[r] - m[r];
                float sign = (labj == labels[grow]) ? 1.f : -1.f;
                if (jcol == grow) sign = 0.f;              // mask diagonal
                bool  p = d > 0.f;
                float e = exp2f(fminf(d, -d) * INV_T_LOG2E);
                float xx = p ? s[r] : sign;
                float yy = p ? sign : s[r];
                s[r] = fmaf(xx, e, yy);                    // online rescale-or-add
                m[r] = fmaxf(m[r], acc[r]);
            }
            minm = m[0];
#pragma unroll
            for (int r = 1; r < 16; ++r) minm = fminf(minm, m[r]);
        }
    };

    // 2-deep register pipeline (rolled x2 body -- R8 showed full unroll
    // blows the I-cache): tile nt+1's loads fly during tile nt's compute.
    lx2 b0[4], b1[4];
    loadB(0, b0);
    for (int nt = 0; nt < NT_PER_CHUNK; nt += 2) {
        loadB(nt + 1, b1);
        computeTile(nt, b0);
        if (nt + 2 < NT_PER_CHUNK) loadB(nt + 2, b0);
        computeTile(nt + 1, b1);
    }

    // merge the 32 column-lane partials of each row (offs stay within l5 half)
#pragma unroll
    for (int off = 1; off < 32; off <<= 1) {
#pragma unroll
        for (int r = 0; r < 16; ++r) {
            float mo = __shfl_xor(m[r], off, 64);
            float so = __shfl_xor(s[r], off, 64);
            float d  = mo - m[r];
            bool  p  = d > 0.f;
            float e  = exp2f(fminf(d, -d) * INV_T_LOG2E);
            s[r] = p ? fmaf(s[r], e, so) : fmaf(so, e, s[r]);
            m[r] = fmaxf(m[r], mo);
        }
    }
    if (lm == 0) {
#pragma unroll
        for (int r = 0; r < 16; ++r) {
            const int grow = row0 + (r & 3) + 8 * (r >> 2) + 4 * l5;
            float* p = partials + ((size_t)grow * NCHUNK + ch) * 2;
            p[0] = m[r];
            p[1] = s[r];
        }
    }
}

// ---- merge chunk-partials per row, reduce, atomic add ----
__global__ __launch_bounds__(256) void merge_kernel(const float* __restrict__ partials,
                                                    float* __restrict__ out) {
    const int g = blockIdx.x * 256 + threadIdx.x;    // row id
    float M = -1e30f, S = 0.f;
#pragma unroll
    for (int c = 0; c < NCHUNK; ++c) {
        const float* p = partials + ((size_t)g * NCHUNK + c) * 2;
        float mo = p[0], so = p[1];
        float d  = mo - M;
        bool  pr = d > 0.f;
        float e  = exp2f(fminf(d, -d) * INV_T_LOG2E);
        S = pr ? fmaf(S, e, so) : fmaf(so, e, S);
        M = fmaxf(M, mo);
    }
    float val = -S * (1.0f / 8192.0f);
#pragma unroll
    for (int off = 1; off < 64; off <<= 1) val += __shfl_xor(val, off, 64);
    __shared__ float red[4];
    if ((threadIdx.x & 63) == 0) red[threadIdx.x >> 6] = val;
    __syncthreads();
    if (threadIdx.x == 0) atomicAdd(out, red[0] + red[1] + red[2] + red[3]);
}

extern "C" void kernel_launch(void* const* d_in, const int* in_sizes, int n_in,
                              void* d_out, int out_size, void* d_ws, size_t ws_size,
                              hipStream_t stream) {
    const float* feat   = (const float*)d_in[0];
    const int*   labels = (const int*)d_in[1];
    float*       out    = (float*)d_out;
    char*        ws     = (char*)d_ws;

    int4*  FB8      = (int4*)ws;                                                 // 1 MB fp8
    float* selfdot  = (float*)(ws + (size_t)M_ROWS * K_DIM);                     // 32 KB
    float* partials = (float*)(ws + (size_t)M_ROWS * K_DIM + M_ROWS * 4);        // 1 MB

    prep_kernel<<<M_ROWS / 32, 256, 0, stream>>>(feat, FB8, selfdot, out);
    fused_kernel<<<(M_ROWS / 128) * NCHUNK, 256, 0, stream>>>(FB8, labels, selfdot, partials);
    merge_kernel<<<M_ROWS / 256, 256, 0, stream>>>(partials, out);
}